// Round 1
// baseline (68.125 us; speedup 1.0000x reference)
//
#include <hip/hip_runtime.h>
#include <hip/hip_bf16.h>

#define NBINS 128
#define TN_ 2.0f
#define TF_ 6.0f
#define FAR_DELTA_ 1e10f

__global__ __launch_bounds__(256) void volrender_kernel(
    const float* __restrict__ ray_o,
    const float* __restrict__ ray_d,
    const float* __restrict__ w_d,
    const float* __restrict__ b_d,
    const float* __restrict__ w_c,
    const float* __restrict__ b_c,
    float* __restrict__ out,
    int N)
{
    int n = blockIdx.x * blockDim.x + threadIdx.x;
    if (n >= N) return;

    // Per-ray data
    const float ox = ray_o[n * 3 + 0];
    const float oy = ray_o[n * 3 + 1];
    const float oz = ray_o[n * 3 + 2];
    const float dx = ray_d[n * 3 + 0];
    const float dy = ray_d[n * 3 + 1];
    const float dz = ray_d[n * 3 + 2];

    // Tiny uniform parameter loads (cached/broadcast)
    const float wd0 = w_d[0], wd1 = w_d[1], wd2 = w_d[2];
    const float bd  = b_d[0];
    float wc[9];
#pragma unroll
    for (int k = 0; k < 9; ++k) wc[k] = w_c[k];
    const float bc0 = b_c[0], bc1 = b_c[1], bc2 = b_c[2];

    // Affine-in-t pre-activations:
    // density input: a_o + t * a_d
    const float a_o = fmaf(oz, wd2, fmaf(oy, wd1, ox * wd0)) + bd;
    const float a_d = fmaf(dz, wd2, fmaf(dy, wd1, dx * wd0));
    // color input j: co[j] + t * cd[j]   (w_c is [3,3] row-major, 'kj' layout)
    float co0 = fmaf(oz, wc[6], fmaf(oy, wc[3], ox * wc[0])) + bc0;
    float co1 = fmaf(oz, wc[7], fmaf(oy, wc[4], ox * wc[1])) + bc1;
    float co2 = fmaf(oz, wc[8], fmaf(oy, wc[5], ox * wc[2])) + bc2;
    float cd0 = fmaf(dz, wc[6], fmaf(dy, wc[3], dx * wc[0]));
    float cd1 = fmaf(dz, wc[7], fmaf(dy, wc[4], dx * wc[1]));
    float cd2 = fmaf(dz, wc[8], fmaf(dy, wc[5], dx * wc[2]));

    const float dt = (TF_ - TN_) / (float)(NBINS - 1);

    float acc = 1.0f;          // exclusive running transmittance
    float o0 = 0.f, o1 = 0.f, o2 = 0.f;

#pragma unroll 4
    for (int i = 0; i < NBINS; ++i) {
        const float t = fmaf((float)i, dt, TN_);

        // density = softplus(a_o + t*a_d), numerically stable form
        const float s  = fmaf(t, a_d, a_o);
        const float sp = fmaxf(s, 0.0f) + __logf(1.0f + __expf(-fabsf(s)));

        const float delta = (i == NBINS - 1) ? FAR_DELTA_ : dt;
        const float T     = __expf(-delta * sp);
        const float w     = acc * (1.0f - T);
        acc *= T;

        // colors = sigmoid(co + t*cd)
        const float e0 = fmaf(t, cd0, co0);
        const float e1 = fmaf(t, cd1, co1);
        const float e2 = fmaf(t, cd2, co2);
        const float c0 = 1.0f / (1.0f + __expf(-e0));
        const float c1 = 1.0f / (1.0f + __expf(-e1));
        const float c2 = 1.0f / (1.0f + __expf(-e2));

        o0 = fmaf(w, c0, o0);
        o1 = fmaf(w, c1, o1);
        o2 = fmaf(w, c2, o2);
    }

    out[n * 3 + 0] = o0;
    out[n * 3 + 1] = o1;
    out[n * 3 + 2] = o2;
}

extern "C" void kernel_launch(void* const* d_in, const int* in_sizes, int n_in,
                              void* d_out, int out_size, void* d_ws, size_t ws_size,
                              hipStream_t stream) {
    const float* ray_o = (const float*)d_in[0];
    const float* ray_d = (const float*)d_in[1];
    const float* w_d   = (const float*)d_in[2];
    const float* b_d   = (const float*)d_in[3];
    const float* w_c   = (const float*)d_in[4];
    const float* b_c   = (const float*)d_in[5];
    // d_in[6] is n_bins (device int32 scalar); fixed at 128 per setup_inputs.

    float* out = (float*)d_out;
    const int N = in_sizes[0] / 3;   // ray_o is [N,3]

    const int block = 256;
    const int grid  = (N + block - 1) / block;
    volrender_kernel<<<grid, block, 0, stream>>>(ray_o, ray_d, w_d, b_d, w_c, b_c, out, N);
}

// Round 3
// 36.246 us; speedup vs baseline: 1.8795x; 1.8795x over previous
//
#include <hip/hip_runtime.h>
#include <hip/hip_bf16.h>

#define NBINS 128
#define TN_ 2.0f
#define TF_ 6.0f
#define FAR_DELTA_ 1e10f
#define LOG2E_ 1.44269504088896340736f

__device__ __forceinline__ float rcp_fast(float x) { return __builtin_amdgcn_rcpf(x); }
__device__ __forceinline__ float exp2_fast(float x) { return __builtin_amdgcn_exp2f(x); }
__device__ __forceinline__ float log2_fast(float x) { return __builtin_amdgcn_logf(x); }

__global__ __launch_bounds__(64) void volrender_kernel(
    const float* __restrict__ ray_o,
    const float* __restrict__ ray_d,
    const float* __restrict__ w_d,
    const float* __restrict__ b_d,
    const float* __restrict__ w_c,
    const float* __restrict__ b_c,
    float* __restrict__ out,
    int N)
{
    int n = blockIdx.x * 64 + threadIdx.x;
    if (n >= N) return;

    const float ox = ray_o[n * 3 + 0];
    const float oy = ray_o[n * 3 + 1];
    const float oz = ray_o[n * 3 + 2];
    const float dx = ray_d[n * 3 + 0];
    const float dy = ray_d[n * 3 + 1];
    const float dz = ray_d[n * 3 + 2];

    const float wd0 = w_d[0], wd1 = w_d[1], wd2 = w_d[2];
    const float bd  = b_d[0];
    float wc[9];
#pragma unroll
    for (int k = 0; k < 9; ++k) wc[k] = w_c[k];
    const float bc0 = b_c[0], bc1 = b_c[1], bc2 = b_c[2];

    // Affine-in-t pre-activations, pre-scaled by log2(e) so every
    // transcendental argument is a single fma.
    const float a_o = fmaf(oz, wd2, fmaf(oy, wd1, ox * wd0)) + bd;
    const float a_d = fmaf(dz, wd2, fmaf(dy, wd1, dx * wd0));
    const float aLo = a_o * LOG2E_;
    const float aLd = a_d * LOG2E_;
    float co0 = fmaf(oz, wc[6], fmaf(oy, wc[3], ox * wc[0])) + bc0;
    float co1 = fmaf(oz, wc[7], fmaf(oy, wc[4], ox * wc[1])) + bc1;
    float co2 = fmaf(oz, wc[8], fmaf(oy, wc[5], ox * wc[2])) + bc2;
    float cd0 = fmaf(dz, wc[6], fmaf(dy, wc[3], dx * wc[0]));
    float cd1 = fmaf(dz, wc[7], fmaf(dy, wc[4], dx * wc[1]));
    float cd2 = fmaf(dz, wc[8], fmaf(dy, wc[5], dx * wc[2]));
    const float nco0 = -co0 * LOG2E_, ncd0 = -cd0 * LOG2E_;
    const float nco1 = -co1 * LOG2E_, ncd1 = -cd1 * LOG2E_;
    const float nco2 = -co2 * LOG2E_, ncd2 = -cd2 * LOG2E_;

    const float dt = (TF_ - TN_) / (float)(NBINS - 1);

    float acc = 1.0f;
    float o0 = 0.f, o1 = 0.f, o2 = 0.f;

    // 4 bins per iteration: transcendental chains independent; only the 4
    // acc-multiplies are serial. Last group peeled for FAR_DELTA.
#pragma unroll 1
    for (int g = 0; g < NBINS - 4; g += 4) {
        float T[4], C0[4], C1[4], C2[4];
#pragma unroll
        for (int k = 0; k < 4; ++k) {
            const float t = fmaf((float)(g + k), dt, TN_);
            // T = exp(-dt*softplus(s)) = exp2(-dt*log2(1+exp2(s*log2e)))
            const float u = exp2_fast(fmaf(t, aLd, aLo));
            const float v = log2_fast(1.0f + u);
            T[k] = exp2_fast(-dt * v);
            C0[k] = rcp_fast(1.0f + exp2_fast(fmaf(t, ncd0, nco0)));
            C1[k] = rcp_fast(1.0f + exp2_fast(fmaf(t, ncd1, nco1)));
            C2[k] = rcp_fast(1.0f + exp2_fast(fmaf(t, ncd2, nco2)));
        }
#pragma unroll
        for (int k = 0; k < 4; ++k) {
            const float w = acc * (1.0f - T[k]);
            acc *= T[k];
            o0 = fmaf(w, C0[k], o0);
            o1 = fmaf(w, C1[k], o1);
            o2 = fmaf(w, C2[k], o2);
        }
    }
    // Tail group: bins 124..127, bin 127 uses FAR_DELTA
    {
        const int g = NBINS - 4;
        float T[4], C0[4], C1[4], C2[4];
#pragma unroll
        for (int k = 0; k < 4; ++k) {
            const float t = fmaf((float)(g + k), dt, TN_);
            const float u = exp2_fast(fmaf(t, aLd, aLo));
            const float v = log2_fast(1.0f + u);
            const float delta = (k == 3) ? FAR_DELTA_ : dt;
            T[k] = exp2_fast(-delta * v);
            C0[k] = rcp_fast(1.0f + exp2_fast(fmaf(t, ncd0, nco0)));
            C1[k] = rcp_fast(1.0f + exp2_fast(fmaf(t, ncd1, nco1)));
            C2[k] = rcp_fast(1.0f + exp2_fast(fmaf(t, ncd2, nco2)));
        }
#pragma unroll
        for (int k = 0; k < 4; ++k) {
            const float w = acc * (1.0f - T[k]);
            acc *= T[k];
            o0 = fmaf(w, C0[k], o0);
            o1 = fmaf(w, C1[k], o1);
            o2 = fmaf(w, C2[k], o2);
        }
    }

    out[n * 3 + 0] = o0;
    out[n * 3 + 1] = o1;
    out[n * 3 + 2] = o2;
}

extern "C" void kernel_launch(void* const* d_in, const int* in_sizes, int n_in,
                              void* d_out, int out_size, void* d_ws, size_t ws_size,
                              hipStream_t stream) {
    const float* ray_o = (const float*)d_in[0];
    const float* ray_d = (const float*)d_in[1];
    const float* w_d   = (const float*)d_in[2];
    const float* b_d   = (const float*)d_in[3];
    const float* w_c   = (const float*)d_in[4];
    const float* b_c   = (const float*)d_in[5];
    // d_in[6] is n_bins (device int32 scalar); fixed at 128 per setup_inputs.

    float* out = (float*)d_out;
    const int N = in_sizes[0] / 3;   // ray_o is [N,3]

    const int block = 64;
    const int grid  = (N + block - 1) / block;
    volrender_kernel<<<grid, block, 0, stream>>>(ray_o, ray_d, w_d, b_d, w_c, b_c, out, N);
}

// Round 4
// 30.315 us; speedup vs baseline: 2.2472x; 1.1957x over previous
//
#include <hip/hip_runtime.h>
#include <hip/hip_bf16.h>

#define NBINS 128
#define TN_ 2.0f
#define TF_ 6.0f
#define FAR_DELTA_ 1e10f
#define LOG2E_ 1.44269504088896340736f
#define BINS_PER_LANE 32   // NBINS / 4 lanes per ray

__device__ __forceinline__ float rcp_fast(float x) { return __builtin_amdgcn_rcpf(x); }
__device__ __forceinline__ float exp2_fast(float x) { return __builtin_amdgcn_exp2f(x); }
__device__ __forceinline__ float log2_fast(float x) { return __builtin_amdgcn_logf(x); }

__global__ __launch_bounds__(256) void volrender_kernel(
    const float* __restrict__ ray_o,
    const float* __restrict__ ray_d,
    const float* __restrict__ w_d,
    const float* __restrict__ b_d,
    const float* __restrict__ w_c,
    const float* __restrict__ b_c,
    float* __restrict__ out,
    int N)
{
    const int tid = blockIdx.x * 256 + threadIdx.x;
    const int n   = tid >> 2;        // ray index
    const int sub = tid & 3;         // quarter-segment index within ray
    if (n >= N) return;

    const float ox = ray_o[n * 3 + 0];
    const float oy = ray_o[n * 3 + 1];
    const float oz = ray_o[n * 3 + 2];
    const float dx = ray_d[n * 3 + 0];
    const float dy = ray_d[n * 3 + 1];
    const float dz = ray_d[n * 3 + 2];

    const float wd0 = w_d[0], wd1 = w_d[1], wd2 = w_d[2];
    const float bd  = b_d[0];
    float wc[9];
#pragma unroll
    for (int k = 0; k < 9; ++k) wc[k] = w_c[k];
    const float bc0 = b_c[0], bc1 = b_c[1], bc2 = b_c[2];

    // Affine-in-t pre-activations, pre-scaled by log2(e):
    const float a_o = fmaf(oz, wd2, fmaf(oy, wd1, ox * wd0)) + bd;
    const float a_d = fmaf(dz, wd2, fmaf(dy, wd1, dx * wd0));
    const float aLo = a_o * LOG2E_;
    const float aLd = a_d * LOG2E_;
    float co0 = fmaf(oz, wc[6], fmaf(oy, wc[3], ox * wc[0])) + bc0;
    float co1 = fmaf(oz, wc[7], fmaf(oy, wc[4], ox * wc[1])) + bc1;
    float co2 = fmaf(oz, wc[8], fmaf(oy, wc[5], ox * wc[2])) + bc2;
    float cd0 = fmaf(dz, wc[6], fmaf(dy, wc[3], dx * wc[0]));
    float cd1 = fmaf(dz, wc[7], fmaf(dy, wc[4], dx * wc[1]));
    float cd2 = fmaf(dz, wc[8], fmaf(dy, wc[5], dx * wc[2]));
    const float nco0 = -co0 * LOG2E_, ncd0 = -cd0 * LOG2E_;
    const float nco1 = -co1 * LOG2E_, ncd1 = -cd1 * LOG2E_;
    const float nco2 = -co2 * LOG2E_, ncd2 = -cd2 * LOG2E_;

    const float dt  = (TF_ - TN_) / (float)(NBINS - 1);
    const float ndt = -dt;
    // delta multiplier for this lane's LAST local bin (global bin 127 only for sub==3)
    const float ndLast = (sub == 3) ? -FAR_DELTA_ : ndt;
    const float t0  = fmaf((float)(sub * BINS_PER_LANE), dt, TN_);

    float P  = 1.0f;                 // local transmittance product over this segment
    float o0 = 0.f, o1 = 0.f, o2 = 0.f;

#define BIN_BODY(ILOC, ND)                                                  \
    {                                                                       \
        const float t = fmaf((float)(ILOC), dt, t0);                        \
        /* density: T = exp2(nd * log2(1 + exp2(s*log2e))) */               \
        const float u = exp2_fast(fmaf(t, aLd, aLo));                       \
        const float v = log2_fast(1.0f + u);                                \
        const float T = exp2_fast((ND) * v);                                \
        const float w = P * (1.0f - T);                                     \
        P *= T;                                                             \
        /* colors via common denominator: w*c_j = w * prod_others * r */    \
        const float x0 = exp2_fast(fmaf(t, ncd0, nco0));                    \
        const float x1 = exp2_fast(fmaf(t, ncd1, nco1));                    \
        const float x2 = exp2_fast(fmaf(t, ncd2, nco2));                    \
        const float A  = 1.0f + x0;                                         \
        const float B  = 1.0f + x1;                                         \
        const float C  = 1.0f + x2;                                         \
        const float BC = B * C;                                             \
        const float r  = rcp_fast(A * BC);                                  \
        const float wr = w * r;                                             \
        o0 = fmaf(BC, wr, o0);                                              \
        o1 = fmaf(A * C, wr, o1);                                           \
        o2 = fmaf(A * B, wr, o2);                                           \
    }

    // 32 local bins: 7 groups of 4 + tail group with ndLast on its last bin
#pragma unroll 1
    for (int g = 0; g < BINS_PER_LANE - 4; g += 4) {
#pragma unroll
        for (int k = 0; k < 4; ++k) {
            BIN_BODY(g + k, ndt);
        }
    }
    {
        const int g = BINS_PER_LANE - 4;
        BIN_BODY(g + 0, ndt);
        BIN_BODY(g + 1, ndt);
        BIN_BODY(g + 2, ndt);
        BIN_BODY(g + 3, ndLast);
    }
#undef BIN_BODY

    // Combine the 4 segments: O = O_lo + P_lo * O_hi, P = P_lo*P_hi
    // step 1: distance 1 within groups of 4 (valid result on sub 0 and 2)
    {
        const float Pn  = __shfl_down(P, 1, 4);
        const float q0  = __shfl_down(o0, 1, 4);
        const float q1  = __shfl_down(o1, 1, 4);
        const float q2  = __shfl_down(o2, 1, 4);
        o0 = fmaf(P, q0, o0);
        o1 = fmaf(P, q1, o1);
        o2 = fmaf(P, q2, o2);
        P *= Pn;
    }
    // step 2: distance 2 (valid on sub 0)
    {
        const float q0 = __shfl_down(o0, 2, 4);
        const float q1 = __shfl_down(o1, 2, 4);
        const float q2 = __shfl_down(o2, 2, 4);
        o0 = fmaf(P, q0, o0);
        o1 = fmaf(P, q1, o1);
        o2 = fmaf(P, q2, o2);
    }

    if (sub == 0) {
        out[n * 3 + 0] = o0;
        out[n * 3 + 1] = o1;
        out[n * 3 + 2] = o2;
    }
}

extern "C" void kernel_launch(void* const* d_in, const int* in_sizes, int n_in,
                              void* d_out, int out_size, void* d_ws, size_t ws_size,
                              hipStream_t stream) {
    const float* ray_o = (const float*)d_in[0];
    const float* ray_d = (const float*)d_in[1];
    const float* w_d   = (const float*)d_in[2];
    const float* b_d   = (const float*)d_in[3];
    const float* w_c   = (const float*)d_in[4];
    const float* b_c   = (const float*)d_in[5];
    // d_in[6] is n_bins (device int32 scalar); fixed at 128 per setup_inputs.

    float* out = (float*)d_out;
    const int N = in_sizes[0] / 3;   // ray_o is [N,3]

    const int threads = N * 4;       // 4 lanes per ray
    const int block = 256;
    const int grid  = (threads + block - 1) / block;
    volrender_kernel<<<grid, block, 0, stream>>>(ray_o, ray_d, w_d, b_d, w_c, b_c, out, N);
}